// Round 1
// baseline (339876.978 us; speedup 1.0000x reference)
//
#include <hip/hip_runtime.h>
#include <hip/hip_bf16.h>
#include <math.h>

// ---------------------------------------------------------------------------
// Persistent bidirectional "batch-as-sequence" LSTM tagger.
//
// Design (round 0):
//  - One cooperative kernel, 256 WGs x 256 threads, 1 WG/CU (145KB LDS each).
//  - WGs 0..127 = forward direction, 128..255 = backward. Each direction-half
//    keeps its Whh0/Whh1 row-slices resident in LDS as bf16, pre-swizzled
//    into thread-read order (conflict-free ds_read_b128).
//  - WG w owns hidden units [w*8, w*8+8) of both layers (32 gate rows each),
//    keeps c locally in LDS, publishes its 8 h values per step to a global
//    slot buffer, custom per-direction atomic barrier between steps.
//  - Per outer step t: pre0 GEMV x16 (Wih0 streamed, L3-hot), 16 layer-0
//    recurrence steps, pre1 GEMV x16 (Wih1 streamed), 16 layer-1 steps,
//    tag GEMV x16 (feedback into next t), barrier.
//  - Final phase: all-barrier then fused log_softmax(fw+bw) into d_out.
// ---------------------------------------------------------------------------

constexpr int B_   = 16;
constexpr int S_   = 256;
constexpr int E_   = 512;
constexpr int H_   = 1024;
constexpr int T_   = 64;
constexpr int DIN0 = E_ + T_;     // 576
constexpr int NTHR = 256;
constexpr int NWGD = 128;         // WGs per direction
constexpr int UPW  = 8;           // hidden units per WG
constexpr int ROWS = 32;          // gate rows per WG (4 gates x 8 units)
constexpr unsigned MAGIC = 0x13572468u;

// LDS byte offsets
constexpr int OFF_W0   = 0;        // uint4[16*256] swizzled bf16x8 Whh0 rows
constexpr int OFF_W1   = 65536;    // uint4[16*256] Whh1 rows
constexpr int OFF_WTG  = 131072;   // float4[2*256] Wih0 tag-columns, swizzled
constexpr int OFF_PRE0 = 139264;   // float[16][32]
constexpr int OFF_PRE1 = 141312;   // float[16][32]
constexpr int OFF_HBUF = 143360;   // float[1024]
constexpr int OFF_PART = 147456;   // float[256]
constexpr int OFF_GROW = 148480;   // float[32]
constexpr int OFF_CELL = 148608;   // float[16]  (c layer0[8], layer1[8])
constexpr int OFF_BIAS = 148672;   // float[64]  (bih+bhh, layer0[32] layer1[32])
constexpr int SMEM_SZ  = 148928;   // < 160 KiB

// workspace float offsets
constexpr size_t WS_H0   = 0;                               // [2][17][H]
constexpr size_t WS_H1   = WS_H0 + (size_t)2 * 17 * H_;     // [2][17][H]
constexpr size_t WS_PREV = WS_H1 + (size_t)2 * 17 * H_;     // [2][B][T]
constexpr size_t WS_OUTD = WS_PREV + (size_t)2 * B_ * T_;   // [2][S][B][T]
constexpr size_t WS_BAR  = WS_OUTD + (size_t)2 * S_ * B_ * T_; // ints[8]

struct Params {
  const float* x;
  const float* Wih0[2]; const float* Whh0[2];
  const float* bih0[2]; const float* bhh0[2];
  const float* Wih1[2]; const float* Whh1[2];
  const float* bih1[2]; const float* bhh1[2];
  const float* Wtg[2];  const float* btg[2];
  float* out; float* ws;
};

__device__ __forceinline__ float sigf(float x) { return 1.0f / (1.0f + expf(-x)); }

__device__ __forceinline__ unsigned short f2bf_rtn(float f) {
  unsigned u = __float_as_uint(f);
  unsigned r = (u + 0x7fffu + ((u >> 16) & 1u)) >> 16;
  return (unsigned short)r;
}
__device__ __forceinline__ unsigned pk2(float a, float b) {
  return (unsigned)f2bf_rtn(a) | ((unsigned)f2bf_rtn(b) << 16);
}

// Inter-workgroup barrier (fence -> arrive -> spin on generation).
// Same protocol as ROCm cooperative-groups grid.sync: data release via
// per-thread device fence + __syncthreads, arrival/release via agent-scope
// atomics (which carry the needed L1/L2 cache maintenance on gfx950).
__device__ __forceinline__ void dbar(int* cnt, int* gen, int n) {
  __threadfence();
  __syncthreads();
  if (threadIdx.x == 0) {
    int g = __hip_atomic_load(gen, __ATOMIC_RELAXED, __HIP_MEMORY_SCOPE_AGENT);
    int a = __hip_atomic_fetch_add(cnt, 1, __ATOMIC_ACQ_REL, __HIP_MEMORY_SCOPE_AGENT);
    if (a == n - 1) {
      __hip_atomic_store(cnt, 0, __ATOMIC_RELAXED, __HIP_MEMORY_SCOPE_AGENT);
      __hip_atomic_store(gen, g + 1, __ATOMIC_RELEASE, __HIP_MEMORY_SCOPE_AGENT);
    } else {
      while (__hip_atomic_load(gen, __ATOMIC_ACQUIRE, __HIP_MEMORY_SCOPE_AGENT) == g)
        __builtin_amdgcn_s_sleep(2);
    }
  }
  __syncthreads();
}

// acc (per thread, mapping tid = o*32 + r) -> dst[r] = addv[r] + sum_o acc
__device__ __forceinline__ void rowsum_to(float acc, float* part, float* dst,
                                          const float* addv, int tid) {
  __syncthreads();            // protect part reuse
  part[tid] = acc;
  __syncthreads();
  if (tid < ROWS) {
    float s = addv[tid];
#pragma unroll
    for (int oo = 0; oo < 8; ++oo) s += part[oo * 32 + tid];
    dst[tid] = s;
  }
  __syncthreads();
}

// 16 sequential LSTM cell steps over the inner (batch-as-sequence) axis.
__device__ __forceinline__ void recur16(const uint4* wm, const float* pre,
                                        float* cell, float* Hs, float* hbuf,
                                        float* part, float* grow, int w,
                                        int tid, int o, int* bcnt, int* bgen) {
#pragma unroll 1
  for (int b = 0; b < B_; ++b) {
    // stage h (written by all WGs last step) into LDS
    ((float4*)hbuf)[tid] = ((const float4*)(Hs + (size_t)b * H_))[tid];
    __syncthreads();
    const float4* hb = (const float4*)(hbuf + o * 128);
    float acc = 0.f;
#pragma unroll
    for (int j = 0; j < 16; ++j) {
      uint4 u = wm[j * NTHR + tid];
      float4 h0 = hb[2 * j], h1 = hb[2 * j + 1];
      acc += __uint_as_float(u.x << 16) * h0.x
           + __uint_as_float(u.x & 0xffff0000u) * h0.y
           + __uint_as_float(u.y << 16) * h0.z
           + __uint_as_float(u.y & 0xffff0000u) * h0.w
           + __uint_as_float(u.z << 16) * h1.x
           + __uint_as_float(u.z & 0xffff0000u) * h1.y
           + __uint_as_float(u.w << 16) * h1.z
           + __uint_as_float(u.w & 0xffff0000u) * h1.w;
    }
    rowsum_to(acc, part, grow, pre + b * ROWS, tid);
    if (tid < UPW) {
      float gi = grow[tid], gf = grow[8 + tid], gg = grow[16 + tid], go = grow[24 + tid];
      float cc = sigf(gf) * cell[tid] + sigf(gi) * tanhf(gg);
      float hh = sigf(go) * tanhf(cc);
      cell[tid] = cc;
      Hs[(size_t)(b + 1) * H_ + w * UPW + tid] = hh;
      if (b == B_ - 1) Hs[w * UPW + tid] = hh;  // carry h to slot 0 for next t
    }
    dbar(bcnt, bgen, NWGD);
  }
}

__global__ void __launch_bounds__(NTHR, 1) lstm_kernel(Params p) {
  extern __shared__ char smem[];
  uint4*  w0m  = (uint4*)(smem + OFF_W0);
  uint4*  w1m  = (uint4*)(smem + OFF_W1);
  float4* wtgs = (float4*)(smem + OFF_WTG);
  float*  pre0 = (float*)(smem + OFF_PRE0);
  float*  pre1 = (float*)(smem + OFF_PRE1);
  float*  hbuf = (float*)(smem + OFF_HBUF);
  float*  part = (float*)(smem + OFF_PART);
  float*  grow = (float*)(smem + OFF_GROW);
  float*  cell = (float*)(smem + OFF_CELL);
  float*  bias = (float*)(smem + OFF_BIAS);

  const int tid = threadIdx.x;
  const int wg  = blockIdx.x;
  const int dir = wg >> 7;
  const int w   = wg & (NWGD - 1);
  const int o   = tid >> 5;   // k-chunk 0..7
  const int r   = tid & 31;   // gate-row 0..31 (gate = r>>3, unit = r&7)
  const int R   = (r >> 3) * H_ + w * UPW + (r & 7);  // global gate row

  const float* Wih0 = p.Wih0[dir];
  const float* Whh0 = p.Whh0[dir];
  const float* Wih1 = p.Wih1[dir];
  const float* Whh1 = p.Whh1[dir];
  const float* Wtg  = p.Wtg[dir];
  const float* btg  = p.btg[dir];

  float* H0   = p.ws + WS_H0 + (size_t)dir * 17 * H_;
  float* H1   = p.ws + WS_H1 + (size_t)dir * 17 * H_;
  float* PREV = p.ws + WS_PREV + (size_t)dir * B_ * T_;
  float* OUTD = p.ws + WS_OUTD;
  int*   bst  = (int*)(p.ws + WS_BAR);
  int*   bcnt = bst + dir * 2;
  int*   bgen = bst + dir * 2 + 1;

  // ---- barrier-state init (ws is poisoned 0xAA before every launch) ----
  if (tid == 0) {
    if (wg == 0) {
#pragma unroll
      for (int i = 0; i < 6; ++i)
        __hip_atomic_store(bst + i, 0, __ATOMIC_RELAXED, __HIP_MEMORY_SCOPE_AGENT);
      __hip_atomic_store(bst + 6, (int)MAGIC, __ATOMIC_RELEASE, __HIP_MEMORY_SCOPE_AGENT);
    } else {
      while (__hip_atomic_load(bst + 6, __ATOMIC_ACQUIRE, __HIP_MEMORY_SCOPE_AGENT) != (int)MAGIC)
        __builtin_amdgcn_s_sleep(8);
    }
  }
  __syncthreads();

  // ---- stage Whh0/Whh1 rows into LDS, bf16-packed, thread-read order ----
  // thread t's j-th uint4 = Whh[R(t)][t.o*128 + j*8 .. +8)
#pragma unroll 1
  for (int j = 0; j < 16; ++j) {
    const float* s0 = Whh0 + (size_t)R * H_ + o * 128 + j * 8;
    uint4 u;
    u.x = pk2(s0[0], s0[1]); u.y = pk2(s0[2], s0[3]);
    u.z = pk2(s0[4], s0[5]); u.w = pk2(s0[6], s0[7]);
    w0m[j * NTHR + tid] = u;
    const float* s1 = Whh1 + (size_t)R * H_ + o * 128 + j * 8;
    u.x = pk2(s1[0], s1[1]); u.y = pk2(s1[2], s1[3]);
    u.z = pk2(s1[4], s1[5]); u.w = pk2(s1[6], s1[7]);
    w1m[j * NTHR + tid] = u;
  }
  // Wih0 tag columns (fp32), swizzled: thread t's jj-th float4
#pragma unroll
  for (int jj = 0; jj < 2; ++jj) {
    const float* s = Wih0 + (size_t)R * DIN0 + E_ + o * 8 + jj * 4;
    wtgs[jj * NTHR + tid] = make_float4(s[0], s[1], s[2], s[3]);
  }
  if (tid < ROWS) {
    int Rr = (tid >> 3) * H_ + w * UPW + (tid & 7);
    bias[tid]        = p.bih0[dir][Rr] + p.bhh0[dir][Rr];
    bias[ROWS + tid] = p.bih1[dir][Rr] + p.bhh1[dir][Rr];
  }
  if (tid < 16) cell[tid] = 0.f;
  if (tid < UPW) {               // h carry slots start at zero
    H0[w * UPW + tid] = 0.f;
    H1[w * UPW + tid] = 0.f;
  }
  dbar(bcnt, bgen, NWGD);

  // =========================== outer time loop ============================
#pragma unroll 1
  for (int t = 0; t < S_; ++t) {
    const int tt = dir ? (S_ - 1 - t) : t;

    // ---- Phase A: pre0[b][r] = Wih0_x . x_t[b] + Wih0_tag . prev[b] + biases
    {
      const float4* wr = (const float4*)(Wih0 + (size_t)R * DIN0 + o * 64);
      float4 wreg[16];
#pragma unroll
      for (int i = 0; i < 16; ++i) wreg[i] = wr[i];
#pragma unroll 1
      for (int b = 0; b < B_; ++b) {
        const float4* xr = (const float4*)(p.x + ((size_t)b * S_ + tt) * E_ + o * 64);
        float acc = 0.f;
#pragma unroll
        for (int i = 0; i < 16; ++i) {
          float4 wv = wreg[i], xv = xr[i];
          acc += wv.x * xv.x + wv.y * xv.y + wv.z * xv.z + wv.w * xv.w;
        }
        if (t > 0) {
          const float4* pv = (const float4*)(PREV + b * T_ + o * 8);
#pragma unroll
          for (int jj = 0; jj < 2; ++jj) {
            float4 wv = wtgs[jj * NTHR + tid];
            float4 qv = pv[jj];
            acc += wv.x * qv.x + wv.y * qv.y + wv.z * qv.z + wv.w * qv.w;
          }
        }
        rowsum_to(acc, part, pre0 + b * ROWS, bias, tid);
      }
    }

    // ---- Phase B: 16 layer-0 recurrence steps
    recur16(w0m, pre0, cell, H0, hbuf, part, grow, w, tid, o, bcnt, bgen);

    // ---- Phase C: pre1[b][r] = Wih1 . h0(t,b) + biases (Wih1 streamed, L3)
    {
      const float4* wr4 = (const float4*)(Wih1 + (size_t)R * H_ + o * 128);
      float4 wreg[32];
#pragma unroll
      for (int i = 0; i < 32; ++i) wreg[i] = wr4[i];
#pragma unroll 1
      for (int b = 0; b < B_; ++b) {
        ((float4*)hbuf)[tid] = ((const float4*)(H0 + (size_t)(b + 1) * H_))[tid];
        __syncthreads();
        const float4* hb = (const float4*)(hbuf + o * 128);
        float acc = 0.f;
#pragma unroll
        for (int i = 0; i < 32; ++i) {
          float4 wv = wreg[i], hv = hb[i];
          acc += wv.x * hv.x + wv.y * hv.y + wv.z * hv.z + wv.w * hv.w;
        }
        rowsum_to(acc, part, pre1 + b * ROWS, bias + ROWS, tid);
      }
    }

    // ---- Phase D: 16 layer-1 recurrence steps
    recur16(w1m, pre1, cell + UPW, H1, hbuf, part, grow, w, tid, o, bcnt, bgen);

    // ---- Phase E: tag output (feedback + stash), WGs 0..15 handle b = w
    if (w < B_) {
      const int b = w;
      ((float4*)hbuf)[tid] = ((const float4*)(H1 + (size_t)(b + 1) * H_))[tid];
      __syncthreads();
      const int tau = tid >> 2, q = tid & 3;
      const float4* wr = (const float4*)(Wtg + (size_t)tau * H_ + q * 256);
      const float4* hb = (const float4*)(hbuf + q * 256);
      float acc = 0.f;
#pragma unroll
      for (int i = 0; i < 64; ++i) {
        float4 wv = wr[i], hv = hb[i];
        acc += wv.x * hv.x + wv.y * hv.y + wv.z * hv.z + wv.w * hv.w;
      }
      acc += __shfl_down(acc, 2, 4);
      acc += __shfl_down(acc, 1, 4);
      if (q == 0) {
        float val = acc + btg[tau];
        OUTD[(((size_t)dir * S_ + tt) * B_ + b) * T_ + tau] = val;
        PREV[b * T_ + tau] = val;
      }
    }
    dbar(bcnt, bgen, NWGD);  // end of t: PREV + carries visible
  }

  // ---- both directions done: combine + log_softmax ----
  dbar(bst + 4, bst + 5, 2 * NWGD);

  const int wave = tid >> 6, lane = tid & 63;
#pragma unroll 1
  for (int i = wave; i < 16; i += 4) {
    int row = wg * 16 + i;        // row = bb*S_ + ss over (B,S)
    int bb = row >> 8, ss = row & 255;
    float z = OUTD[(((size_t)0 * S_ + ss) * B_ + bb) * T_ + lane]
            + OUTD[(((size_t)1 * S_ + ss) * B_ + bb) * T_ + lane];
    float m = z;
#pragma unroll
    for (int d = 32; d >= 1; d >>= 1) m = fmaxf(m, __shfl_xor(m, d, 64));
    float e = expf(z - m);
    float sum = e;
#pragma unroll
    for (int d = 32; d >= 1; d >>= 1) sum += __shfl_xor(sum, d, 64);
    p.out[(size_t)row * T_ + lane] = (z - m) - logf(sum);
  }
}

extern "C" void kernel_launch(void* const* d_in, const int* in_sizes, int n_in,
                              void* d_out, int out_size, void* d_ws, size_t ws_size,
                              hipStream_t stream) {
  (void)in_sizes; (void)n_in; (void)out_size; (void)ws_size;
  Params prm;
  prm.x = (const float*)d_in[0];
  for (int d = 0; d < 2; ++d) {
    int base = 1 + d * 10;
    prm.Wih0[d] = (const float*)d_in[base + 0];
    prm.Whh0[d] = (const float*)d_in[base + 1];
    prm.bih0[d] = (const float*)d_in[base + 2];
    prm.bhh0[d] = (const float*)d_in[base + 3];
    prm.Wih1[d] = (const float*)d_in[base + 4];
    prm.Whh1[d] = (const float*)d_in[base + 5];
    prm.bih1[d] = (const float*)d_in[base + 6];
    prm.bhh1[d] = (const float*)d_in[base + 7];
    prm.Wtg[d]  = (const float*)d_in[base + 8];
    prm.btg[d]  = (const float*)d_in[base + 9];
  }
  prm.out = (float*)d_out;
  prm.ws  = (float*)d_ws;

  hipFuncSetAttribute((const void*)lstm_kernel,
                      hipFuncAttributeMaxDynamicSharedMemorySize, SMEM_SZ);
  void* kp[] = { &prm };
  hipLaunchCooperativeKernel((const void*)lstm_kernel, dim3(2 * NWGD), dim3(NTHR),
                             kp, SMEM_SZ, stream);
}

// Round 3
// 78485.803 us; speedup vs baseline: 4.3304x; 4.3304x over previous
//
#include <hip/hip_runtime.h>
#include <hip/hip_bf16.h>
#include <math.h>

// ---------------------------------------------------------------------------
// Persistent bidirectional batch-as-sequence LSTM tagger — round 3.
//
// Round-2 bug: tag GEMV at k==17 used hbuf1 (= h1(b=15)) for ALL b. Fix:
// compute tag(b=k-2) at step k (hbuf1 holds exactly h1(b=k-2) then). WG w<64
// owns tag row w (Wtg row in 4 fp32 VGPRs/thread), wave-0 reduction, tid0
// publishes PREV (ordered by the same wave-0 release flag) + writes OUTD.
//
// Sync: producers publish h via relaxed agent-scope atomic stores, one
// release flag per WG per step; consumers poll 128 flags in parallel, one
// acquire fence, then plain vector loads. 18 steps per t.
// ---------------------------------------------------------------------------

constexpr int B_   = 16;
constexpr int S_   = 256;
constexpr int E_   = 512;
constexpr int H_   = 1024;
constexpr int T_   = 64;
constexpr int DIN0 = E_ + T_;     // 576
constexpr int NTHR = 256;
constexpr int NWGD = 128;         // WGs per direction
constexpr int UPW  = 8;
constexpr int ROWS = 32;
constexpr unsigned MAGIC = 0x13572468u;

// LDS byte offsets
constexpr int OFF_W0   = 0;        // uint4[16*256]  Whh0 bf16 swizzled
constexpr int OFF_W1   = 65536;    // uint4[16*256]  Whh1
constexpr int OFF_HB0  = 131072;   // float[1024]    h0 stage
constexpr int OFF_HB1  = 135168;   // float[1024]    h1 stage
constexpr int OFF_PRE0 = 139264;   // float[16][32]  pre0 (bias folded in)
constexpr int OFF_PA   = 141312;   // float[256]
constexpr int OFF_PB   = 142336;   // float[256]
constexpr int OFF_PREV = 143360;   // float[16][64]  prev tag stage
constexpr int OFF_GROW = 147456;   // float[64]
constexpr int OFF_BIAS = 147712;   // float[64]
constexpr int OFF_CELL = 147968;   // float[16]
constexpr int OFF_POLL = 148032;   // int
constexpr int OFF_TAGP = 148096;   // float[256] tag partials
constexpr int SMEM_SZ  = 149120;

// workspace float offsets
constexpr size_t WS_H0S   = 0;                       // [2dir][2slot][1024]
constexpr size_t WS_H1S   = 4096;                    // [2dir][2slot][1024]
constexpr size_t WS_PREV  = 8192;                    // [2dir][16][64]
constexpr size_t WS_OUTD  = 10240;                   // [2dir][256][16][64]
constexpr size_t WS_FLAGS = 10240 + 524288;          // ints [2dir][128*16]
constexpr size_t WS_BST   = WS_FLAGS + 4096;         // ints[8]

struct Params {
  const float* x;
  const float* Wih0[2]; const float* Whh0[2];
  const float* bih0[2]; const float* bhh0[2];
  const float* Wih1[2]; const float* Whh1[2];
  const float* bih1[2]; const float* bhh1[2];
  const float* Wtg[2];  const float* btg[2];
  float* out; float* ws;
};

__device__ __forceinline__ float sigf(float x) { return 1.0f / (1.0f + expf(-x)); }

__device__ __forceinline__ unsigned short f2bf_rtn(float f) {
  unsigned u = __float_as_uint(f);
  unsigned r = (u + 0x7fffu + ((u >> 16) & 1u)) >> 16;
  return (unsigned short)r;
}
__device__ __forceinline__ unsigned pk2(float a, float b) {
  return (unsigned)f2bf_rtn(a) | ((unsigned)f2bf_rtn(b) << 16);
}

// dot of 8 packed-bf16 weights against 8 fp32 h values
__device__ __forceinline__ float d8(uint4 u, float4 a, float4 b) {
  float s;
  s  = __uint_as_float(u.x << 16) * a.x + __uint_as_float(u.x & 0xffff0000u) * a.y;
  s += __uint_as_float(u.y << 16) * a.z + __uint_as_float(u.y & 0xffff0000u) * a.w;
  s += __uint_as_float(u.z << 16) * b.x + __uint_as_float(u.z & 0xffff0000u) * b.y;
  s += __uint_as_float(u.w << 16) * b.z + __uint_as_float(u.w & 0xffff0000u) * b.w;
  return s;
}

// One-time barriers (init / final): counter-based is fine off the hot path.
__device__ __forceinline__ void dbar(int* cnt, int* gen, int n) {
  __threadfence();
  __syncthreads();
  if (threadIdx.x == 0) {
    int g = __hip_atomic_load(gen, __ATOMIC_RELAXED, __HIP_MEMORY_SCOPE_AGENT);
    int a = __hip_atomic_fetch_add(cnt, 1, __ATOMIC_ACQ_REL, __HIP_MEMORY_SCOPE_AGENT);
    if (a == n - 1) {
      __hip_atomic_store(cnt, 0, __ATOMIC_RELAXED, __HIP_MEMORY_SCOPE_AGENT);
      __hip_atomic_store(gen, g + 1, __ATOMIC_RELEASE, __HIP_MEMORY_SCOPE_AGENT);
    } else {
      while (__hip_atomic_load(gen, __ATOMIC_ACQUIRE, __HIP_MEMORY_SCOPE_AGENT) == g)
        __builtin_amdgcn_s_sleep(2);
    }
  }
  __syncthreads();
}

__global__ void __launch_bounds__(NTHR, 1) lstm_kernel(Params p) {
  extern __shared__ char smem[];
  uint4* w0m   = (uint4*)(smem + OFF_W0);
  uint4* w1m   = (uint4*)(smem + OFF_W1);
  float* hbuf0 = (float*)(smem + OFF_HB0);
  float* hbuf1 = (float*)(smem + OFF_HB1);
  float* pre0  = (float*)(smem + OFF_PRE0);
  float* partA = (float*)(smem + OFF_PA);
  float* partB = (float*)(smem + OFF_PB);
  float* prevL = (float*)(smem + OFF_PREV);
  float* grow  = (float*)(smem + OFF_GROW);
  float* bias  = (float*)(smem + OFF_BIAS);
  float* cell  = (float*)(smem + OFF_CELL);
  float* tagp  = (float*)(smem + OFF_TAGP);
  volatile int* poll = (volatile int*)(smem + OFF_POLL);

  const int tid = threadIdx.x;
  const int wg  = blockIdx.x;
  const int dir = wg >> 7;
  const int w   = wg & (NWGD - 1);
  const int o   = tid >> 5;                            // k-chunk 0..7
  const int r   = tid & 31;                            // gate-row 0..31
  const int R   = (r >> 3) * H_ + w * UPW + (r & 7);   // global gate row

  const float* Wih0 = p.Wih0[dir];
  const float* Whh0 = p.Whh0[dir];
  const float* Wih1 = p.Wih1[dir];
  const float* Whh1 = p.Whh1[dir];
  const float* Wtg  = p.Wtg[dir];
  const float* btg  = p.btg[dir];

  float* H0S  = p.ws + WS_H0S + (size_t)dir * 2048;    // [2][1024]
  float* H1S  = p.ws + WS_H1S + (size_t)dir * 2048;
  float* PREV = p.ws + WS_PREV + (size_t)dir * B_ * T_;
  float* OUTD = p.ws + WS_OUTD;
  int* FLAGS  = (int*)(p.ws + WS_FLAGS) + (size_t)dir * 2048;  // stride 16 ints
  int* bst    = (int*)(p.ws + WS_BST);

  // ---- barrier-state init (ws poisoned 0xAA; 0xAAAAAAAA<0 so flags need
  //      no zeroing — poll target starts at 1) ----
  if (tid == 0) {
    if (wg == 0) {
#pragma unroll
      for (int i = 0; i < 6; ++i)
        __hip_atomic_store(bst + i, 0, __ATOMIC_RELAXED, __HIP_MEMORY_SCOPE_AGENT);
      __hip_atomic_store(bst + 6, (int)MAGIC, __ATOMIC_RELEASE, __HIP_MEMORY_SCOPE_AGENT);
    } else {
      while (__hip_atomic_load(bst + 6, __ATOMIC_ACQUIRE, __HIP_MEMORY_SCOPE_AGENT) != (int)MAGIC)
        __builtin_amdgcn_s_sleep(8);
    }
  }

  // ---- stage Whh0/Whh1 into LDS (bf16, thread-read order); Wih1 into VGPRs
  uint4 wih1r[16];
#pragma unroll 1
  for (int j = 0; j < 16; ++j) {
    const float* s0 = Whh0 + (size_t)R * H_ + o * 128 + j * 8;
    uint4 u;
    u.x = pk2(s0[0], s0[1]); u.y = pk2(s0[2], s0[3]);
    u.z = pk2(s0[4], s0[5]); u.w = pk2(s0[6], s0[7]);
    w0m[j * NTHR + tid] = u;
    const float* s1 = Whh1 + (size_t)R * H_ + o * 128 + j * 8;
    u.x = pk2(s1[0], s1[1]); u.y = pk2(s1[2], s1[3]);
    u.z = pk2(s1[4], s1[5]); u.w = pk2(s1[6], s1[7]);
    w1m[j * NTHR + tid] = u;
    const float* s2 = Wih1 + (size_t)R * H_ + o * 128 + j * 8;
    u.x = pk2(s2[0], s2[1]); u.y = pk2(s2[2], s2[3]);
    u.z = pk2(s2[4], s2[5]); u.w = pk2(s2[6], s2[7]);
    wih1r[j] = u;
  }
  // tag row w (WGs w<64): Wtg row in 4 fp32 regs/thread + bias
  float4 wtag = make_float4(0.f, 0.f, 0.f, 0.f);
  float btgw = 0.f;
  if (w < T_) {
    wtag = *(const float4*)(Wtg + (size_t)w * H_ + tid * 4);
    btgw = btg[w];
  }
  if (tid < ROWS) {
    int Rr = (tid >> 3) * H_ + w * UPW + (tid & 7);
    bias[tid]        = p.bih0[dir][Rr] + p.bhh0[dir][Rr];
    bias[ROWS + tid] = p.bih1[dir][Rr] + p.bhh1[dir][Rr];
  }
  if (tid < 16) cell[tid] = 0.f;
  if (tid < UPW) {                 // zero the slots read at t=0
    H0S[1024 + w * UPW + tid] = 0.f;   // h0 slot 1 (read at k=0)
    H1S[0    + w * UPW + tid] = 0.f;   // h1 slot 0 (read at k=1)
  }
  dbar(bst + 0, bst + 1, 2 * NWGD);

  // initial prefetch (emulates end of k=17): hbuf0 <- h0 slot1
  ((float4*)hbuf0)[tid] = ((const float4*)(H0S + 1024))[tid];
  __syncthreads();

  int flagval = 1;

  // =========================== outer time loop ============================
#pragma unroll 1
  for (int t = 0; t < S_; ++t) {
    const int tt = dir ? (S_ - 1 - t) : t;

    // ---- Phase A: pre0[b][r] = bias0 + Wih0_x.x_t[b] (+ Wih0_tag.prev[b])
    {
      const int b  = tid >> 4, rh = tid & 15;
      const int r0 = 2 * rh, r1 = 2 * rh + 1;
      const int R0 = (r0 >> 3) * H_ + w * UPW + (r0 & 7);
      const int R1 = (r1 >> 3) * H_ + w * UPW + (r1 & 7);
      const float4* w0p = (const float4*)(Wih0 + (size_t)R0 * DIN0);
      const float4* w1p = (const float4*)(Wih0 + (size_t)R1 * DIN0);
      const float4* xp  = (const float4*)(p.x + ((size_t)b * S_ + tt) * E_);
      float s0 = bias[r0], s1 = bias[r1];
#pragma unroll 8
      for (int i = 0; i < 128; ++i) {
        float4 xv = xp[i], a = w0p[i], c = w1p[i];
        s0 += a.x * xv.x + a.y * xv.y + a.z * xv.z + a.w * xv.w;
        s1 += c.x * xv.x + c.y * xv.y + c.z * xv.z + c.w * xv.w;
      }
      if (t > 0) {
        const float4* pv = (const float4*)(prevL + b * T_);
        const float4* q0 = (const float4*)(Wih0 + (size_t)R0 * DIN0 + E_);
        const float4* q1 = (const float4*)(Wih0 + (size_t)R1 * DIN0 + E_);
#pragma unroll
        for (int i = 0; i < 16; ++i) {
          float4 pvv = pv[i], a = q0[i], c = q1[i];
          s0 += a.x * pvv.x + a.y * pvv.y + a.z * pvv.z + a.w * pvv.w;
          s1 += c.x * pvv.x + c.y * pvv.y + c.z * pvv.z + c.w * pvv.w;
        }
      }
      pre0[b * ROWS + r0] = s0;
      pre0[b * ROWS + r1] = s1;
      __syncthreads();
    }

    // ---- 18 pipelined steps: L0(b=k), L1(b=k-1), tag(b=k-2) ----
#pragma unroll 1
    for (int k = 0; k < 18; ++k) {
      float acc0 = 0.f, accB = 0.f;
      const float4* hb0 = ((const float4*)hbuf0) + o * 32;
      const float4* hb1 = ((const float4*)hbuf1) + o * 32;
      if (k >= 1 && k < 16) {
#pragma unroll
        for (int j = 0; j < 16; ++j) {
          float4 a0 = hb0[2 * j], a1 = hb0[2 * j + 1];
          acc0 += d8(w0m[j * NTHR + tid], a0, a1);
          accB += d8(wih1r[j], a0, a1);
          float4 b0 = hb1[2 * j], b1 = hb1[2 * j + 1];
          accB += d8(w1m[j * NTHR + tid], b0, b1);
        }
      } else if (k == 0) {
#pragma unroll
        for (int j = 0; j < 16; ++j) {
          float4 a0 = hb0[2 * j], a1 = hb0[2 * j + 1];
          acc0 += d8(w0m[j * NTHR + tid], a0, a1);
        }
      } else if (k == 16) {
#pragma unroll
        for (int j = 0; j < 16; ++j) {
          float4 a0 = hb0[2 * j], a1 = hb0[2 * j + 1];
          accB += d8(wih1r[j], a0, a1);
          float4 b0 = hb1[2 * j], b1 = hb1[2 * j + 1];
          accB += d8(w1m[j * NTHR + tid], b0, b1);
        }
      }
      // k == 17: no recurrence dots

      // tag partial for b = k-2 (hbuf1 == h1(b=k-2)); WGs w<64 own row w
      float tagd = 0.f;
      if (k >= 2 && w < T_) {
        float4 hv = *(const float4*)(hbuf1 + tid * 4);
        tagd = wtag.x * hv.x + wtag.y * hv.y + wtag.z * hv.z + wtag.w * hv.w;
      }

      __syncthreads();
      partA[tid] = acc0;
      partB[tid] = accB;
      tagp[tid]  = tagd;
      __syncthreads();

      // wave-0 reductions
      if (tid < 32) {
        float s = pre0[(k < 16 ? k : 15) * ROWS + tid];
#pragma unroll
        for (int oo = 0; oo < 8; ++oo) s += partA[oo * 32 + tid];
        grow[tid] = s;
      } else if (tid < 64) {
        int rr = tid - 32;
        float s = bias[ROWS + rr];
#pragma unroll
        for (int oo = 0; oo < 8; ++oo) s += partB[oo * 32 + rr];
        grow[32 + rr] = s;
      }
      if (k >= 2 && w < T_ && tid < 64) {
        float ts = tagp[tid] + tagp[64 + tid] + tagp[128 + tid] + tagp[192 + tid];
#pragma unroll
        for (int d = 32; d >= 1; d >>= 1) ts += __shfl_xor(ts, d, 64);
        if (tid == 0) {
          const int b = k - 2;
          float val = ts + btgw;
          OUTD[(((size_t)dir * S_ + tt) * B_ + b) * T_ + w] = val;  // plain
          __hip_atomic_store(PREV + b * T_ + w, val,
                             __ATOMIC_RELAXED, __HIP_MEMORY_SCOPE_AGENT);
        }
      }
      __syncthreads();

      // cell updates + publishes (wave 0 only -> ordered by tid0's release)
      if (k < 16 && tid < UPW) {
        int u = tid;
        float gi = grow[u], gf = grow[8 + u], gg = grow[16 + u], go = grow[24 + u];
        float cc = sigf(gf) * cell[u] + sigf(gi) * tanhf(gg);
        float hh = sigf(go) * tanhf(cc);
        cell[u] = cc;
        __hip_atomic_store(H0S + (k & 1) * 1024 + w * UPW + u, hh,
                           __ATOMIC_RELAXED, __HIP_MEMORY_SCOPE_AGENT);
      }
      if (k >= 1 && k < 17 && tid >= UPW && tid < 16) {
        int u = tid - UPW;
        float gi = grow[32 + u], gf = grow[40 + u], gg = grow[48 + u], go = grow[56 + u];
        float cc = sigf(gf) * cell[8 + u] + sigf(gi) * tanhf(gg);
        float hh = sigf(go) * tanhf(cc);
        cell[8 + u] = cc;
        __hip_atomic_store(H1S + (k & 1) * 1024 + w * UPW + u, hh,
                           __ATOMIC_RELAXED, __HIP_MEMORY_SCOPE_AGENT);
      }
      // release: orders wave-0's stores (all publishers are wave 0)
      if (tid == 0)
        __hip_atomic_store(FLAGS + w * 16, flagval,
                           __ATOMIC_RELEASE, __HIP_MEMORY_SCOPE_AGENT);

      // ---- poll all 128 flags of this direction (parallel, O(1) depth) ----
      for (int it = 0;; ++it) {
        bool ok = true;
        if (tid < NWGD)
          ok = __hip_atomic_load(FLAGS + tid * 16, __ATOMIC_RELAXED,
                                 __HIP_MEMORY_SCOPE_AGENT) >= flagval;
        __syncthreads();
        if (tid == 0) *poll = 0;
        __syncthreads();
        if (!ok) *poll = 1;
        __syncthreads();
        if (*poll == 0) break;
        if (it > 0) __builtin_amdgcn_s_sleep(2);
      }
      ++flagval;
      __builtin_amdgcn_fence(__ATOMIC_ACQUIRE, "agent");  // inv caches

      // ---- prefetch slots for next step (slot = k&1) ----
      {
        const int sl = (k & 1) * 1024;
        ((float4*)hbuf0)[tid] = ((const float4*)(H0S + sl))[tid];
        ((float4*)hbuf1)[tid] = ((const float4*)(H1S + sl))[tid];
        if (k == 17)
          ((float4*)prevL)[tid] = ((const float4*)PREV)[tid];
      }
      __syncthreads();
    }
  }

  // ---- both directions done: combine + log_softmax ----
  dbar(bst + 2, bst + 3, 2 * NWGD);

  const int wave = tid >> 6, lane = tid & 63;
#pragma unroll 1
  for (int i = wave; i < 16; i += 4) {
    int row = wg * 16 + i;        // row = bb*S_ + ss over (B,S)
    int bb = row >> 8, ss = row & 255;
    float z = OUTD[(((size_t)0 * S_ + ss) * B_ + bb) * T_ + lane]
            + OUTD[(((size_t)1 * S_ + ss) * B_ + bb) * T_ + lane];
    float m = z;
#pragma unroll
    for (int d = 32; d >= 1; d >>= 1) m = fmaxf(m, __shfl_xor(m, d, 64));
    float e = expf(z - m);
    float sum = e;
#pragma unroll
    for (int d = 32; d >= 1; d >>= 1) sum += __shfl_xor(sum, d, 64);
    p.out[(size_t)row * T_ + lane] = (z - m) - logf(sum);
  }
}

extern "C" void kernel_launch(void* const* d_in, const int* in_sizes, int n_in,
                              void* d_out, int out_size, void* d_ws, size_t ws_size,
                              hipStream_t stream) {
  (void)in_sizes; (void)n_in; (void)out_size; (void)ws_size;
  Params prm;
  prm.x = (const float*)d_in[0];
  for (int d = 0; d < 2; ++d) {
    int base = 1 + d * 10;
    prm.Wih0[d] = (const float*)d_in[base + 0];
    prm.Whh0[d] = (const float*)d_in[base + 1];
    prm.bih0[d] = (const float*)d_in[base + 2];
    prm.bhh0[d] = (const float*)d_in[base + 3];
    prm.Wih1[d] = (const float*)d_in[base + 4];
    prm.Whh1[d] = (const float*)d_in[base + 5];
    prm.bih1[d] = (const float*)d_in[base + 6];
    prm.bhh1[d] = (const float*)d_in[base + 7];
    prm.Wtg[d]  = (const float*)d_in[base + 8];
    prm.btg[d]  = (const float*)d_in[base + 9];
  }
  prm.out = (float*)d_out;
  prm.ws  = (float*)d_ws;

  hipFuncSetAttribute((const void*)lstm_kernel,
                      hipFuncAttributeMaxDynamicSharedMemorySize, SMEM_SZ);
  void* kp[] = { &prm };
  hipLaunchCooperativeKernel((const void*)lstm_kernel, dim3(2 * NWGD), dim3(NTHR),
                             kp, SMEM_SZ, stream);
}

// Round 5
// 37051.843 us; speedup vs baseline: 9.1730x; 2.1183x over previous
//
#include <hip/hip_runtime.h>
#include <math.h>

// ---------------------------------------------------------------------------
// Persistent bidirectional batch-as-sequence LSTM tagger — round 5.
//
// Structure: EXACTLY round 3 (known good): 18 steps/t, in-loop tag at
// k=2..17 (b=k-2), prevL staged at k=17, same __syncthreads placement,
// same final dbar + log_softmax. ONLY the inter-WG transport changed:
//   round 3: relaxed h-stores + release flag + parallel poll + acquire fence
//            (16.3us/step: 4 serialized MALL trips, per-step buffer_inv
//             evicts L2 -> 3.7GB Wih0 refetch)
//   round 5: RCCL-style LL: each value is ONE 8-B atomic {fp32, u32 gen}
//            (sc1, relaxed). Consumers poll the data itself. No fences in
//            the hot path at all -> weights stay L2-resident.
// Slot safety: H0/H1 use 2 slots keyed by k&1 (18 even => fixed mapping);
// a slot written at step g is rewritten at g+2, and the g+2 publisher has
// passed step g+1's full-WG consume, which transitively requires every WG
// to have consumed slot g. PREV double-buffers by t&1, consumed at k=17.
// ---------------------------------------------------------------------------

constexpr int B_   = 16;
constexpr int S_   = 256;
constexpr int E_   = 512;
constexpr int H_   = 1024;
constexpr int T_   = 64;
constexpr int DIN0 = E_ + T_;     // 576
constexpr int NTHR = 256;
constexpr int NWGD = 128;
constexpr int UPW  = 8;
constexpr int ROWS = 32;
constexpr unsigned MAGIC = 0x13572468u;

// LDS byte offsets
constexpr int OFF_W0    = 0;        // uint4[16*256]  Whh0 bf16 swizzled
constexpr int OFF_W1    = 65536;    // uint4[16*256]  Whh1
constexpr int OFF_HB0   = 131072;   // float[1024]    h0 stage
constexpr int OFF_HB1   = 135168;   // float[1024]    h1 stage
constexpr int OFF_PRE0  = 139264;   // float[16][32]
constexpr int OFF_PA    = 141312;   // float[256]
constexpr int OFF_PB    = 142336;   // float[256]
constexpr int OFF_TAGP  = 143360;   // float[256]
constexpr int OFF_PREVL = 144384;   // float[16][64]
constexpr int OFF_GROW  = 148480;   // float[64]
constexpr int OFF_BIAS  = 148736;   // float[64]
constexpr int OFF_CELL  = 148992;   // float[16]
constexpr int SMEM_SZ   = 149120;

// workspace BYTE offsets
constexpr size_t WS_OUTD = 0;                    // float[2][256][16][64] = 2 MB
constexpr size_t WS_H0LL = 2097152;              // ull[2dir][2slot][1024]
constexpr size_t WS_H1LL = WS_H0LL + 32768;      // ull[2dir][2slot][1024]
constexpr size_t WS_PRLL = WS_H1LL + 32768;      // ull[2dir][2buf][1024]
constexpr size_t WS_BST  = WS_PRLL + 32768;      // ints[8]

struct Params {
  const float* x;
  const float* Wih0[2]; const float* Whh0[2];
  const float* bih0[2]; const float* bhh0[2];
  const float* Wih1[2]; const float* Whh1[2];
  const float* bih1[2]; const float* bhh1[2];
  const float* Wtg[2];  const float* btg[2];
  float* out; float* ws;
};

__device__ __forceinline__ float sigf(float x) { return 1.0f / (1.0f + expf(-x)); }

__device__ __forceinline__ unsigned short f2bf_rtn(float f) {
  unsigned u = __float_as_uint(f);
  unsigned r = (u + 0x7fffu + ((u >> 16) & 1u)) >> 16;
  return (unsigned short)r;
}
__device__ __forceinline__ unsigned pk2(float a, float b) {
  return (unsigned)f2bf_rtn(a) | ((unsigned)f2bf_rtn(b) << 16);
}

__device__ __forceinline__ float d8(uint4 u, float4 a, float4 b) {
  float s;
  s  = __uint_as_float(u.x << 16) * a.x + __uint_as_float(u.x & 0xffff0000u) * a.y;
  s += __uint_as_float(u.y << 16) * a.z + __uint_as_float(u.y & 0xffff0000u) * a.w;
  s += __uint_as_float(u.z << 16) * b.x + __uint_as_float(u.z & 0xffff0000u) * b.y;
  s += __uint_as_float(u.w << 16) * b.z + __uint_as_float(u.w & 0xffff0000u) * b.w;
  return s;
}

// ---- LL primitives: 8-B atomic {payload, gen} ----
__device__ __forceinline__ unsigned long long llld(const unsigned long long* p) {
  return __hip_atomic_load(p, __ATOMIC_RELAXED, __HIP_MEMORY_SCOPE_AGENT);
}
__device__ __forceinline__ void llst(unsigned long long* p, float v, unsigned gen) {
  unsigned long long pkt =
      (unsigned long long)__float_as_uint(v) | ((unsigned long long)gen << 32);
  __hip_atomic_store(p, pkt, __ATOMIC_RELAXED, __HIP_MEMORY_SCOPE_AGENT);
}
__device__ __forceinline__ void consume4(const unsigned long long* src,
                                         unsigned gen, float* dst) {
  unsigned long long a0 = llld(src + 0), a1 = llld(src + 1);
  unsigned long long a2 = llld(src + 2), a3 = llld(src + 3);
  while ((unsigned)(a0 >> 32) != gen) a0 = llld(src + 0);
  while ((unsigned)(a1 >> 32) != gen) a1 = llld(src + 1);
  while ((unsigned)(a2 >> 32) != gen) a2 = llld(src + 2);
  while ((unsigned)(a3 >> 32) != gen) a3 = llld(src + 3);
  dst[0] = __uint_as_float((unsigned)a0);
  dst[1] = __uint_as_float((unsigned)a1);
  dst[2] = __uint_as_float((unsigned)a2);
  dst[3] = __uint_as_float((unsigned)a3);
}

// One-time barrier (final combine only) — known-good from rounds 1/3.
__device__ __forceinline__ void dbar(int* cnt, int* gen, int n) {
  __threadfence();
  __syncthreads();
  if (threadIdx.x == 0) {
    int g = __hip_atomic_load(gen, __ATOMIC_RELAXED, __HIP_MEMORY_SCOPE_AGENT);
    int a = __hip_atomic_fetch_add(cnt, 1, __ATOMIC_ACQ_REL, __HIP_MEMORY_SCOPE_AGENT);
    if (a == n - 1) {
      __hip_atomic_store(cnt, 0, __ATOMIC_RELAXED, __HIP_MEMORY_SCOPE_AGENT);
      __hip_atomic_store(gen, g + 1, __ATOMIC_RELEASE, __HIP_MEMORY_SCOPE_AGENT);
    } else {
      while (__hip_atomic_load(gen, __ATOMIC_ACQUIRE, __HIP_MEMORY_SCOPE_AGENT) == g)
        __builtin_amdgcn_s_sleep(2);
    }
  }
  __syncthreads();
}

__global__ void __launch_bounds__(NTHR, 1) lstm_kernel(Params p) {
  extern __shared__ char smem[];
  uint4* w0m   = (uint4*)(smem + OFF_W0);
  uint4* w1m   = (uint4*)(smem + OFF_W1);
  float* hbuf0 = (float*)(smem + OFF_HB0);
  float* hbuf1 = (float*)(smem + OFF_HB1);
  float* pre0  = (float*)(smem + OFF_PRE0);
  float* partA = (float*)(smem + OFF_PA);
  float* partB = (float*)(smem + OFF_PB);
  float* tagp  = (float*)(smem + OFF_TAGP);
  float* prevL = (float*)(smem + OFF_PREVL);
  float* grow  = (float*)(smem + OFF_GROW);
  float* bias  = (float*)(smem + OFF_BIAS);
  float* cell  = (float*)(smem + OFF_CELL);

  const int tid = threadIdx.x;
  const int wg  = blockIdx.x;
  const int dir = wg >> 7;
  const int w   = wg & (NWGD - 1);
  const int o   = tid >> 5;                            // k-chunk 0..7
  const int r   = tid & 31;                            // gate-row 0..31
  const int R   = (r >> 3) * H_ + w * UPW + (r & 7);   // global gate row

  const float* Wih0 = p.Wih0[dir];
  const float* Whh0 = p.Whh0[dir];
  const float* Wih1 = p.Wih1[dir];
  const float* Whh1 = p.Whh1[dir];
  const float* Wtg  = p.Wtg[dir];
  const float* btg  = p.btg[dir];

  char* wsb = (char*)p.ws;
  float* OUTD = (float*)(wsb + WS_OUTD);
  unsigned long long* H0LL = (unsigned long long*)(wsb + WS_H0LL) + dir * 2048;
  unsigned long long* H1LL = (unsigned long long*)(wsb + WS_H1LL) + dir * 2048;
  unsigned long long* PRLL = (unsigned long long*)(wsb + WS_PRLL) + dir * 2048;
  int* bst = (int*)(wsb + WS_BST);

  // ---- bst init handshake (for the final dbar; ws poisoned 0xAA) ----
  if (tid == 0) {
    if (wg == 0) {
#pragma unroll
      for (int i = 0; i < 6; ++i)
        __hip_atomic_store(bst + i, 0, __ATOMIC_RELAXED, __HIP_MEMORY_SCOPE_AGENT);
      __hip_atomic_store(bst + 6, (int)MAGIC, __ATOMIC_RELEASE, __HIP_MEMORY_SCOPE_AGENT);
    } else {
      while (__hip_atomic_load(bst + 6, __ATOMIC_ACQUIRE, __HIP_MEMORY_SCOPE_AGENT) != (int)MAGIC)
        __builtin_amdgcn_s_sleep(8);
    }
  }

  // ---- stage Whh0/Whh1 into LDS (bf16, thread-read order); Wih1 into VGPRs
  uint4 wih1r[16];
#pragma unroll 1
  for (int j = 0; j < 16; ++j) {
    const float* s0 = Whh0 + (size_t)R * H_ + o * 128 + j * 8;
    uint4 u;
    u.x = pk2(s0[0], s0[1]); u.y = pk2(s0[2], s0[3]);
    u.z = pk2(s0[4], s0[5]); u.w = pk2(s0[6], s0[7]);
    w0m[j * NTHR + tid] = u;
    const float* s1 = Whh1 + (size_t)R * H_ + o * 128 + j * 8;
    u.x = pk2(s1[0], s1[1]); u.y = pk2(s1[2], s1[3]);
    u.z = pk2(s1[4], s1[5]); u.w = pk2(s1[6], s1[7]);
    w1m[j * NTHR + tid] = u;
    const float* s2 = Wih1 + (size_t)R * H_ + o * 128 + j * 8;
    u.x = pk2(s2[0], s2[1]); u.y = pk2(s2[2], s2[3]);
    u.z = pk2(s2[4], s2[5]); u.w = pk2(s2[6], s2[7]);
    wih1r[j] = u;
  }
  // tag row w (WGs w<64): Wtg row in 4 fp32 regs/thread + bias
  float4 wtag = make_float4(0.f, 0.f, 0.f, 0.f);
  float btgw = 0.f;
  if (w < T_) {
    wtag = *(const float4*)(Wtg + (size_t)w * H_ + tid * 4);
    btgw = btg[w];
  }
  if (tid < ROWS) {
    int Rr = (tid >> 3) * H_ + w * UPW + (tid & 7);
    bias[tid]        = p.bih0[dir][Rr] + p.bhh0[dir][Rr];
    bias[ROWS + tid] = p.bih1[dir][Rr] + p.bhh1[dir][Rr];
  }
  if (tid < 16) cell[tid] = 0.f;
  // initial h state = 0 (local; LL gens gate all cross-WG reads)
  ((float4*)hbuf0)[tid] = make_float4(0.f, 0.f, 0.f, 0.f);
  ((float4*)hbuf1)[tid] = make_float4(0.f, 0.f, 0.f, 0.f);
  __syncthreads();

  // =========================== outer time loop ============================
#pragma unroll 1
  for (int t = 0; t < S_; ++t) {
    const int tt = dir ? (S_ - 1 - t) : t;

    // ---- Phase A: pre0[b][r] = bias0 + Wih0_x.x_t[b] (+ Wih0_tag.prev[b])
    {
      const int b  = tid >> 4, rh = tid & 15;
      const int r0 = 2 * rh, r1 = 2 * rh + 1;
      const int R0 = (r0 >> 3) * H_ + w * UPW + (r0 & 7);
      const int R1 = (r1 >> 3) * H_ + w * UPW + (r1 & 7);
      const float4* w0p = (const float4*)(Wih0 + (size_t)R0 * DIN0);
      const float4* w1p = (const float4*)(Wih0 + (size_t)R1 * DIN0);
      const float4* xp  = (const float4*)(p.x + ((size_t)b * S_ + tt) * E_);
      float s0 = bias[r0], s1 = bias[r1];
#pragma unroll 8
      for (int i = 0; i < 128; ++i) {
        float4 xv = xp[i], a = w0p[i], c = w1p[i];
        s0 += a.x * xv.x + a.y * xv.y + a.z * xv.z + a.w * xv.w;
        s1 += c.x * xv.x + c.y * xv.y + c.z * xv.z + c.w * xv.w;
      }
      if (t > 0) {
        const float4* pv = (const float4*)(prevL + b * T_);
        const float4* q0 = (const float4*)(Wih0 + (size_t)R0 * DIN0 + E_);
        const float4* q1 = (const float4*)(Wih0 + (size_t)R1 * DIN0 + E_);
#pragma unroll
        for (int i = 0; i < 16; ++i) {
          float4 pvv = pv[i], a = q0[i], c = q1[i];
          s0 += a.x * pvv.x + a.y * pvv.y + a.z * pvv.z + a.w * pvv.w;
          s1 += c.x * pvv.x + c.y * pvv.y + c.z * pvv.z + c.w * pvv.w;
        }
      }
      pre0[b * ROWS + r0] = s0;
      pre0[b * ROWS + r1] = s1;
      __syncthreads();
    }

    // ---- 18 pipelined steps: L0(b=k), L1(b=k-1), tag(b=k-2) ----
#pragma unroll 1
    for (int k = 0; k < 18; ++k) {
      const unsigned gen  = (unsigned)(t * 18 + k) + 1u;
      const int      slot = (k & 1) << 10;

      float acc0 = 0.f, accB = 0.f;
      const float4* hb0 = ((const float4*)hbuf0) + o * 32;
      const float4* hb1 = ((const float4*)hbuf1) + o * 32;
      if (k >= 1 && k < 16) {
#pragma unroll
        for (int j = 0; j < 16; ++j) {
          float4 a0 = hb0[2 * j], a1 = hb0[2 * j + 1];
          acc0 += d8(w0m[j * NTHR + tid], a0, a1);
          accB += d8(wih1r[j], a0, a1);
          float4 b0 = hb1[2 * j], b1 = hb1[2 * j + 1];
          accB += d8(w1m[j * NTHR + tid], b0, b1);
        }
      } else if (k == 0) {
#pragma unroll
        for (int j = 0; j < 16; ++j) {
          float4 a0 = hb0[2 * j], a1 = hb0[2 * j + 1];
          acc0 += d8(w0m[j * NTHR + tid], a0, a1);
        }
      } else if (k == 16) {
#pragma unroll
        for (int j = 0; j < 16; ++j) {
          float4 a0 = hb0[2 * j], a1 = hb0[2 * j + 1];
          accB += d8(wih1r[j], a0, a1);
          float4 b0 = hb1[2 * j], b1 = hb1[2 * j + 1];
          accB += d8(w1m[j * NTHR + tid], b0, b1);
        }
      }
      // k == 17: no recurrence dots

      // tag partial for b = k-2 (hbuf1 == h1(b=k-2)); WGs w<64 own row w
      float tagd = 0.f;
      if (k >= 2 && w < T_) {
        float4 hv = *(const float4*)(hbuf1 + tid * 4);
        tagd = wtag.x * hv.x + wtag.y * hv.y + wtag.z * hv.z + wtag.w * hv.w;
      }

      partA[tid] = acc0;
      partB[tid] = accB;
      tagp[tid]  = tagd;
      __syncthreads();               // S1: dots done (hbuf free), partials out

      // ---- wave-0 reductions (round-3 layout) ----
      if (tid < 32) {
        if (k < 16) {
          float s = pre0[k * ROWS + tid];
#pragma unroll
          for (int oo = 0; oo < 8; ++oo) s += partA[oo * 32 + tid];
          grow[tid] = s;
        }
      } else if (tid < 64) {
        int rr = tid - 32;
        if (k >= 1 && k < 17) {
          float s = bias[ROWS + rr];
#pragma unroll
          for (int oo = 0; oo < 8; ++oo) s += partB[oo * 32 + rr];
          grow[32 + rr] = s;
        }
      }
      if (k >= 2 && w < T_ && tid < 64) {
        float ts = tagp[tid] + tagp[64 + tid] + tagp[128 + tid] + tagp[192 + tid];
#pragma unroll
        for (int d = 32; d >= 1; d >>= 1) ts += __shfl_xor(ts, d, 64);
        if (tid == 0) {
          const int b = k - 2;
          float val = ts + btgw;
          OUTD[(((size_t)dir * S_ + tt) * B_ + b) * T_ + w] = val;  // plain
          llst(PRLL + ((t & 1) << 10) + b * T_ + w, val, (unsigned)(t + 1));
        }
      }
      __syncthreads();               // S2: grow visible (round-3 placement)

      // ---- cell updates + LL publishes ----
      if (k < 16 && tid < UPW) {
        int u = tid;
        float gi = grow[u], gf = grow[8 + u], gg = grow[16 + u], go = grow[24 + u];
        float cc = sigf(gf) * cell[u] + sigf(gi) * tanhf(gg);
        float hh = sigf(go) * tanhf(cc);
        cell[u] = cc;
        llst(H0LL + slot + w * UPW + u, hh, gen);
      }
      if (k >= 1 && k < 17 && tid >= UPW && tid < 16) {
        int u = tid - UPW;
        float gi = grow[32 + u], gf = grow[40 + u], gg = grow[48 + u], go = grow[56 + u];
        float cc = sigf(gf) * cell[8 + u] + sigf(gi) * tanhf(gg);
        float hh = sigf(go) * tanhf(cc);
        cell[8 + u] = cc;
        llst(H1LL + slot + w * UPW + u, hh, gen);
      }

      // ---- LL consume into hbuf/prevL (data arrives with its gen) ----
      if (k < 16)
        consume4(H0LL + slot + tid * 4, gen, hbuf0 + tid * 4);
      if (k >= 1 && k < 17)
        consume4(H1LL + slot + tid * 4, gen, hbuf1 + tid * 4);
      if (k == 17)
        consume4(PRLL + ((t & 1) << 10) + tid * 4, (unsigned)(t + 1),
                 prevL + tid * 4);
      __syncthreads();               // S3: hbuf/prevL coherent for next step
    }
  }

  // ---- both directions done: combine + log_softmax (round-3 verbatim) ----
  dbar(bst + 2, bst + 3, 2 * NWGD);

  const int wave = tid >> 6, lane = tid & 63;
#pragma unroll 1
  for (int i = wave; i < 16; i += 4) {
    int row = wg * 16 + i;        // row = bb*S_ + ss over (B,S)
    int bb = row >> 8, ss = row & 255;
    float z = OUTD[(((size_t)0 * S_ + ss) * B_ + bb) * T_ + lane]
            + OUTD[(((size_t)1 * S_ + ss) * B_ + bb) * T_ + lane];
    float m = z;
#pragma unroll
    for (int d = 32; d >= 1; d >>= 1) m = fmaxf(m, __shfl_xor(m, d, 64));
    float e = expf(z - m);
    float sum = e;
#pragma unroll
    for (int d = 32; d >= 1; d >>= 1) sum += __shfl_xor(sum, d, 64);
    p.out[(size_t)row * T_ + lane] = (z - m) - logf(sum);
  }
}

extern "C" void kernel_launch(void* const* d_in, const int* in_sizes, int n_in,
                              void* d_out, int out_size, void* d_ws, size_t ws_size,
                              hipStream_t stream) {
  (void)in_sizes; (void)n_in; (void)out_size; (void)ws_size;
  Params prm;
  prm.x = (const float*)d_in[0];
  for (int d = 0; d < 2; ++d) {
    int base = 1 + d * 10;
    prm.Wih0[d] = (const float*)d_in[base + 0];
    prm.Whh0[d] = (const float*)d_in[base + 1];
    prm.bih0[d] = (const float*)d_in[base + 2];
    prm.bhh0[d] = (const float*)d_in[base + 3];
    prm.Wih1[d] = (const float*)d_in[base + 4];
    prm.Whh1[d] = (const float*)d_in[base + 5];
    prm.bih1[d] = (const float*)d_in[base + 6];
    prm.bhh1[d] = (const float*)d_in[base + 7];
    prm.Wtg[d]  = (const float*)d_in[base + 8];
    prm.btg[d]  = (const float*)d_in[base + 9];
  }
  prm.out = (float*)d_out;
  prm.ws  = (float*)d_ws;

  hipFuncSetAttribute((const void*)lstm_kernel,
                      hipFuncAttributeMaxDynamicSharedMemorySize, SMEM_SZ);
  void* kp[] = { &prm };
  hipLaunchCooperativeKernel((const void*)lstm_kernel, dim3(2 * NWGD), dim3(NTHR),
                             kp, SMEM_SZ, stream);
}